// Round 3
// baseline (37.115 us; speedup 1.0000x reference)
//
#include <hip/hip_runtime.h>
#include <math.h>

#define B_ 128
#define K_ 2048
#define TEMP_ 0.07f
#define EPS_ 1e-12f
#define NBLK_ 1024   // k_pairs grid: 128 i * 8 j-groups

// ---------------------------------------------------------------------------
// K1: row-wise L2 normalize f[i,:] = feat[i,:]/max(||feat||,EPS).
// Block 0 also zeroes the completion counter for K2 (same-stream kernel
// boundary makes it visible device-wide before K2 starts).
// ---------------------------------------------------------------------------
__global__ __launch_bounds__(256) void k_norm(const float* __restrict__ feat,
                                              float* __restrict__ f,
                                              unsigned* __restrict__ counter) {
    const int i = blockIdx.x;
    const int tid = threadIdx.x;
    if (i == 0 && tid == 0)
        __hip_atomic_store(counter, 0u, __ATOMIC_RELAXED, __HIP_MEMORY_SCOPE_AGENT);
    const float4* src = reinterpret_cast<const float4*>(feat + (size_t)i * K_);
    float4* dst = reinterpret_cast<float4*>(f + (size_t)i * K_);
    float4 v0 = src[tid];
    float4 v1 = src[tid + 256];
    float s = v0.x * v0.x + v0.y * v0.y + v0.z * v0.z + v0.w * v0.w
            + v1.x * v1.x + v1.y * v1.y + v1.z * v1.z + v1.w * v1.w;
#pragma unroll
    for (int o = 1; o < 64; o <<= 1) s += __shfl_xor(s, o, 64);
    __shared__ float wsum[4];
    const int wave = tid >> 6, lane = tid & 63;
    if (lane == 0) wsum[wave] = s;
    __syncthreads();
    const float tot = wsum[0] + wsum[1] + wsum[2] + wsum[3];
    const float rn = 1.0f / fmaxf(sqrtf(tot), EPS_);
    v0.x *= rn; v0.y *= rn; v0.z *= rn; v0.w *= rn;
    v1.x *= rn; v1.y *= rn; v1.z *= rn; v1.w *= rn;
    dst[tid] = v0;
    dst[tid + 256] = v1;
}

// ---------------------------------------------------------------------------
// K2: pair kernel + fused finale (last-finishing block reduces partials).
// Grid 1024: blk = i*8 + jg. 256 threads = 4 waves; wave w owns 4 j's.
// LDS: a=f_i, g=1+f_i^3, h=f_i^2 (24 KB). After writing its partials each
// block release-increments `counter`; the block seeing old==1023 acquires
// and performs the final log/sum reduction into out[0]. Deterministic:
// the finale reads a fully-written part[] in fixed order.
// ---------------------------------------------------------------------------
__global__ __launch_bounds__(256, 4) void k_pairs(const float* __restrict__ f,
                                                  float* __restrict__ part,
                                                  unsigned* __restrict__ counter,
                                                  float* __restrict__ out) {
    const int blk = blockIdx.x;
    const int i = blk >> 3;
    const int jg = blk & 7;
    const int tid = threadIdx.x;
    const int wave = tid >> 6, lane = tid & 63;

    __shared__ float sa[K_];
    __shared__ float sg[K_];
    __shared__ float sh[K_];
    {
        const float4* fi4 = reinterpret_cast<const float4*>(f + (size_t)i * K_);
        float4* a4 = reinterpret_cast<float4*>(sa);
        float4* g4 = reinterpret_cast<float4*>(sg);
        float4* h4 = reinterpret_cast<float4*>(sh);
#pragma unroll
        for (int t = 0; t < 2; ++t) {
            const int idx = tid + t * 256;
            float4 a = fi4[idx];
            float4 g, h;
            h.x = a.x * a.x; h.y = a.y * a.y; h.z = a.z * a.z; h.w = a.w * a.w;
            g.x = 1.0f + h.x * a.x; g.y = 1.0f + h.y * a.y;
            g.z = 1.0f + h.z * a.z; g.w = 1.0f + h.w * a.w;
            a4[idx] = a; g4[idx] = g; h4[idx] = h;
        }
    }
    __syncthreads();

    const int j0 = jg * 16 + wave * 4;
    const float4* b0 = reinterpret_cast<const float4*>(f + (size_t)(j0 + 0) * K_);
    const float4* b1 = reinterpret_cast<const float4*>(f + (size_t)(j0 + 1) * K_);
    const float4* b2 = reinterpret_cast<const float4*>(f + (size_t)(j0 + 2) * K_);
    const float4* b3 = reinterpret_cast<const float4*>(f + (size_t)(j0 + 3) * K_);

    const float4* a4 = reinterpret_cast<const float4*>(sa);
    const float4* g4 = reinterpret_cast<const float4*>(sg);
    const float4* h4 = reinterpret_cast<const float4*>(sh);

    float du[4] = {0.f, 0.f, 0.f, 0.f};
    float uu[4] = {0.f, 0.f, 0.f, 0.f};
    float dv[4] = {0.f, 0.f, 0.f, 0.f};
    float vv[4] = {0.f, 0.f, 0.f, 0.f};

#pragma unroll
    for (int c = 0; c < 8; ++c) {
        const int idx = c * 64 + lane;
        const float4 a = a4[idx];
        const float4 g = g4[idx];
        const float4 h = h4[idx];
        float4 bb[4];
        bb[0] = b0[idx]; bb[1] = b1[idx]; bb[2] = b2[idx]; bb[3] = b3[idx];
#pragma unroll
        for (int t = 0; t < 4; ++t) {
#define ACC1(AX, GX, HX, BX)                                \
            {                                               \
                const float u = (BX) * (GX);                \
                du[t] = fmaf((AX), u, du[t]);               \
                uu[t] = fmaf(u, u, uu[t]);                  \
                const float t0 = (HX) * (BX);               \
                const float v = fmaf(t0, (BX), (BX));       \
                dv[t] = fmaf((AX), v, dv[t]);               \
                vv[t] = fmaf(v, v, vv[t]);                  \
            }
            ACC1(a.x, g.x, h.x, bb[t].x)
            ACC1(a.y, g.y, h.y, bb[t].y)
            ACC1(a.z, g.z, h.z, bb[t].z)
            ACC1(a.w, g.w, h.w, bb[t].w)
#undef ACC1
        }
    }

#pragma unroll
    for (int o = 1; o < 64; o <<= 1) {
#pragma unroll
        for (int t = 0; t < 4; ++t) {
            du[t] += __shfl_xor(du[t], o, 64);
            uu[t] += __shfl_xor(uu[t], o, 64);
            dv[t] += __shfl_xor(dv[t], o, 64);
            vv[t] += __shfl_xor(vv[t], o, 64);
        }
    }

    const float inv_t = 1.0f / TEMP_;
    float s1 = 0.f, s2 = 0.f;
#pragma unroll
    for (int t = 0; t < 4; ++t) {
        const float ds = du[t] / fmaxf(sqrtf(uu[t]), EPS_) * inv_t;
        const float dn = dv[t] / fmaxf(sqrtf(vv[t]), EPS_) * inv_t;
        s1 += ds;
        s2 += __expf(ds) + 3.0f * __expf(dn);
    }

    __shared__ float p1[4], p2[4];
    __shared__ int s_last;
    if (lane == 0) { p1[wave] = s1; p2[wave] = s2; }
    __syncthreads();
    if (tid == 0) {
        const float t1 = p1[0] + p1[1] + p1[2] + p1[3];
        const float t2 = p2[0] + p2[1] + p2[2] + p2[3];
        __hip_atomic_store(&part[blk * 2 + 0], t1, __ATOMIC_RELAXED, __HIP_MEMORY_SCOPE_AGENT);
        __hip_atomic_store(&part[blk * 2 + 1], t2, __ATOMIC_RELAXED, __HIP_MEMORY_SCOPE_AGENT);
        const unsigned old = __hip_atomic_fetch_add(counter, 1u, __ATOMIC_ACQ_REL,
                                                    __HIP_MEMORY_SCOPE_AGENT);
        s_last = (old == (unsigned)(NBLK_ - 1));
    }
    __syncthreads();
    if (!s_last) return;

    // ---- finale: this is the last block to finish; part[] is complete ----
    float c = 0.0f;
    if (tid < B_) {
        float f1 = 0.f, f2 = 0.f;
#pragma unroll
        for (int q = 0; q < 8; ++q) {
            f1 += __hip_atomic_load(&part[(tid * 8 + q) * 2 + 0], __ATOMIC_RELAXED,
                                    __HIP_MEMORY_SCOPE_AGENT);
            f2 += __hip_atomic_load(&part[(tid * 8 + q) * 2 + 1], __ATOMIC_RELAXED,
                                    __HIP_MEMORY_SCOPE_AGENT);
        }
        c = f1 * (1.0f / B_) - __logf(f2);
    }
#pragma unroll
    for (int o = 1; o < 64; o <<= 1) c += __shfl_xor(c, o, 64);
    if (lane == 0) p1[wave] = c;     // reuse p1 as wave-sum scratch
    __syncthreads();
    if (tid == 0)
        out[0] = -(p1[0] + p1[1] + p1[2] + p1[3]) * (1.0f / B_);
}

extern "C" void kernel_launch(void* const* d_in, const int* in_sizes, int n_in,
                              void* d_out, int out_size, void* d_ws, size_t ws_size,
                              hipStream_t stream) {
    const float* feat = (const float*)d_in[0];
    float* f = (float*)d_ws;                       // 128*2048 floats = 1 MB
    float* part = f + (size_t)B_ * K_;             // 1024*2 floats
    unsigned* counter = (unsigned*)(part + NBLK_ * 2);
    float* out = (float*)d_out;

    k_norm<<<B_, 256, 0, stream>>>(feat, f, counter);
    k_pairs<<<NBLK_, 256, 0, stream>>>(f, part, counter, out);
}

// Round 4
// 24.782 us; speedup vs baseline: 1.4977x; 1.4977x over previous
//
#include <hip/hip_runtime.h>
#include <math.h>

#define B_ 128
#define K_ 2048
#define TEMP_ 0.07f
#define EPS_ 1e-12f
#define NBLK_ 1024   // 128 i * 8 j-groups

// ---------------------------------------------------------------------------
// K2: pair kernel, v4 — reads RAW feat (no separate normalize kernel).
// Grid 1024: blk = i*8 + jg. 256 threads = 4 waves; wave w owns 4 j's.
//
// Math (all normalization folded into block-local sums):
//   a = x_i / ||x_i||          (i-row, staged in LDS with g = 1+a^3, h = a^2)
//   w_k = b_k * g_k            (b = raw x_j; 1/n_j prefactor cancels)
//   ds  = (Σ a·w) / max(||w||,eps) / T
//   q_k = h_k * b_k^2,  c = 1/max(sqrt(Σ b^2),eps)   (= 1/n_j, same pass!)
//   dv  = c·S_aq + S_ab
//   vv  = c^2·S_qq + 2c·S_qb + S_bb
//   dn  = dv / max(sqrt(vv),eps) / T
// Per-(i,jg) partials: Σ_j ds  and  Σ_j (e^ds + 3 e^dn).
// ---------------------------------------------------------------------------
__global__ __launch_bounds__(256, 4) void k_pairs(const float* __restrict__ feat,
                                                  float* __restrict__ part) {
    const int blk = blockIdx.x;
    const int i = blk >> 3;
    const int jg = blk & 7;
    const int tid = threadIdx.x;
    const int wave = tid >> 6, lane = tid & 63;

    __shared__ float sa[K_];
    __shared__ float sg[K_];
    __shared__ float sh[K_];
    __shared__ float wsum[4];

    // ---- stage i-row: block-local norm, then a/g/h into LDS ----
    {
        const float4* fi4 = reinterpret_cast<const float4*>(feat + (size_t)i * K_);
        float4 v0 = fi4[tid];
        float4 v1 = fi4[tid + 256];
        float s = v0.x * v0.x + v0.y * v0.y + v0.z * v0.z + v0.w * v0.w
                + v1.x * v1.x + v1.y * v1.y + v1.z * v1.z + v1.w * v1.w;
#pragma unroll
        for (int o = 1; o < 64; o <<= 1) s += __shfl_xor(s, o, 64);
        if (lane == 0) wsum[wave] = s;
        __syncthreads();
        const float tot = wsum[0] + wsum[1] + wsum[2] + wsum[3];
        const float rn = 1.0f / fmaxf(sqrtf(tot), EPS_);

        float4* a4 = reinterpret_cast<float4*>(sa);
        float4* g4 = reinterpret_cast<float4*>(sg);
        float4* h4 = reinterpret_cast<float4*>(sh);
#define STAGE(V, IDX)                                                   \
        {                                                               \
            float4 a, g, h;                                             \
            a.x = (V).x * rn; a.y = (V).y * rn;                         \
            a.z = (V).z * rn; a.w = (V).w * rn;                         \
            h.x = a.x * a.x; h.y = a.y * a.y;                           \
            h.z = a.z * a.z; h.w = a.w * a.w;                           \
            g.x = 1.0f + h.x * a.x; g.y = 1.0f + h.y * a.y;             \
            g.z = 1.0f + h.z * a.z; g.w = 1.0f + h.w * a.w;             \
            a4[IDX] = a; g4[IDX] = g; h4[IDX] = h;                      \
        }
        STAGE(v0, tid)
        STAGE(v1, tid + 256)
#undef STAGE
    }
    __syncthreads();

    const int j0 = jg * 16 + wave * 4;
    const float4* b0 = reinterpret_cast<const float4*>(feat + (size_t)(j0 + 0) * K_);
    const float4* b1 = reinterpret_cast<const float4*>(feat + (size_t)(j0 + 1) * K_);
    const float4* b2 = reinterpret_cast<const float4*>(feat + (size_t)(j0 + 2) * K_);
    const float4* b3 = reinterpret_cast<const float4*>(feat + (size_t)(j0 + 3) * K_);

    const float4* a4 = reinterpret_cast<const float4*>(sa);
    const float4* g4 = reinterpret_cast<const float4*>(sg);
    const float4* h4 = reinterpret_cast<const float4*>(sh);

    float du[4]  = {0.f, 0.f, 0.f, 0.f};
    float uu[4]  = {0.f, 0.f, 0.f, 0.f};
    float sab[4] = {0.f, 0.f, 0.f, 0.f};
    float saq[4] = {0.f, 0.f, 0.f, 0.f};
    float sqq[4] = {0.f, 0.f, 0.f, 0.f};
    float sqb[4] = {0.f, 0.f, 0.f, 0.f};
    float sbb[4] = {0.f, 0.f, 0.f, 0.f};

#pragma unroll
    for (int c = 0; c < 8; ++c) {
        const int idx = c * 64 + lane;
        const float4 a = a4[idx];
        const float4 g = g4[idx];
        const float4 h = h4[idx];
        float4 bb[4];
        bb[0] = b0[idx]; bb[1] = b1[idx]; bb[2] = b2[idx]; bb[3] = b3[idx];
#pragma unroll
        for (int t = 0; t < 4; ++t) {
#define ACC1(AX, GX, HX, BX)                                 \
            {                                                \
                const float w = (BX) * (GX);                 \
                du[t]  = fmaf((AX), w, du[t]);               \
                uu[t]  = fmaf(w, w, uu[t]);                  \
                const float t0 = (HX) * (BX);                \
                const float q  = t0 * (BX);                  \
                saq[t] = fmaf((AX), q, saq[t]);              \
                sqq[t] = fmaf(q, q, sqq[t]);                 \
                sqb[t] = fmaf(q, (BX), sqb[t]);              \
                sbb[t] = fmaf((BX), (BX), sbb[t]);           \
                sab[t] = fmaf((AX), (BX), sab[t]);           \
            }
            ACC1(a.x, g.x, h.x, bb[t].x)
            ACC1(a.y, g.y, h.y, bb[t].y)
            ACC1(a.z, g.z, h.z, bb[t].z)
            ACC1(a.w, g.w, h.w, bb[t].w)
#undef ACC1
        }
    }

#pragma unroll
    for (int o = 1; o < 64; o <<= 1) {
#pragma unroll
        for (int t = 0; t < 4; ++t) {
            du[t]  += __shfl_xor(du[t],  o, 64);
            uu[t]  += __shfl_xor(uu[t],  o, 64);
            sab[t] += __shfl_xor(sab[t], o, 64);
            saq[t] += __shfl_xor(saq[t], o, 64);
            sqq[t] += __shfl_xor(sqq[t], o, 64);
            sqb[t] += __shfl_xor(sqb[t], o, 64);
            sbb[t] += __shfl_xor(sbb[t], o, 64);
        }
    }

    const float inv_t = 1.0f / TEMP_;
    float s1 = 0.f, s2 = 0.f;
#pragma unroll
    for (int t = 0; t < 4; ++t) {
        const float ds = du[t] / fmaxf(sqrtf(uu[t]), EPS_) * inv_t;
        const float c  = 1.0f / fmaxf(sqrtf(sbb[t]), EPS_);
        const float dv = fmaf(c, saq[t], sab[t]);
        const float vv = fmaf(c * c, sqq[t], fmaf(2.0f * c, sqb[t], sbb[t]));
        const float dn = dv / fmaxf(sqrtf(vv), EPS_) * inv_t;
        s1 += ds;
        s2 += __expf(ds) + 3.0f * __expf(dn);
    }

    __shared__ float p1[4], p2[4];
    if (lane == 0) { p1[wave] = s1; p2[wave] = s2; }
    __syncthreads();
    if (tid == 0) {
        part[blk * 2 + 0] = p1[0] + p1[1] + p1[2] + p1[3];
        part[blk * 2 + 1] = p2[0] + p2[1] + p2[2] + p2[3];
    }
}

// ---------------------------------------------------------------------------
// K3: final. thread i combines its 8 group-partials, computes
// contrib_i = (1/B) * sum_j d_self - log(denom_i), reduces over i.
// ---------------------------------------------------------------------------
__global__ __launch_bounds__(128) void k_final(const float* __restrict__ part,
                                               float* __restrict__ out) {
    const int i = threadIdx.x;
    float s1 = 0.0f, s2 = 0.0f;
#pragma unroll
    for (int q = 0; q < 8; ++q) {
        s1 += part[(i * 8 + q) * 2 + 0];
        s2 += part[(i * 8 + q) * 2 + 1];
    }
    float c = s1 * (1.0f / B_) - __logf(s2);
#pragma unroll
    for (int o = 1; o < 64; o <<= 1) c += __shfl_xor(c, o, 64);
    __shared__ float wsum[2];
    const int wave = i >> 6, lane = i & 63;
    if (lane == 0) wsum[wave] = c;
    __syncthreads();
    if (i == 0) out[0] = -(wsum[0] + wsum[1]) * (1.0f / B_);
}

extern "C" void kernel_launch(void* const* d_in, const int* in_sizes, int n_in,
                              void* d_out, int out_size, void* d_ws, size_t ws_size,
                              hipStream_t stream) {
    const float* feat = (const float*)d_in[0];
    float* part = (float*)d_ws;              // 1024*2 floats
    float* out = (float*)d_out;

    k_pairs<<<NBLK_, 256, 0, stream>>>(feat, part);
    k_final<<<1, 128, 0, stream>>>(part, out);
}

// Round 5
// 21.317 us; speedup vs baseline: 1.7411x; 1.1625x over previous
//
#include <hip/hip_runtime.h>
#include <math.h>

#define B_ 128
#define K_ 2048
#define TEMP_ 0.07f
#define EPS_ 1e-12f
#define NBLK_ 1024   // 128 i * 8 j-groups

// ---------------------------------------------------------------------------
// k_pairs v5: 16-lane-group-per-j layout.
// Grid 1024: blk = i*8 + jg. 256 threads = 4 waves; each wave owns 4 j's,
// one per 16-lane group (grp = lane>>4). Each lane accumulates a k-slice
// (stride-16 float4s) of ONE j -> only 7 accumulators/lane, and the
// cross-lane reduce is 4 butterfly steps within the group (28 shuffles)
// instead of 6 steps x 28 accums (168 shuffles).
//
// Math identical to v4 (absmax 0.0), with h eliminated via q=(a*b)^2:
//   a = x_i/||x_i|| (block-local), g = 1+a^3   (only 2 LDS arrays, 16 KB)
//   w = b*g;  p = a*b;  q = p*p            (b = raw x_j)
//   du=S(a w), uu=S(w^2), sab=S(p), saq=S(a q), sqq=S(q^2), sqb=S(q b),
//   sbb=S(b^2);  c = 1/max(sqrt(sbb),eps)
//   ds = du/max(sqrt(uu),eps)/T
//   dn = (c*saq + sab)/max(sqrt(c^2*sqq + 2c*sqb + sbb),eps)/T
// Partials per (i,jg): sum_j ds, sum_j (e^ds + 3 e^dn).
// ---------------------------------------------------------------------------
__global__ __launch_bounds__(256, 4) void k_pairs(const float* __restrict__ feat,
                                                  float* __restrict__ part) {
    const int blk = blockIdx.x;
    const int i = blk >> 3;
    const int jg = blk & 7;
    const int tid = threadIdx.x;
    const int wave = tid >> 6, lane = tid & 63;
    const int s = lane & 15;      // sublane within 16-lane group
    const int grp = lane >> 4;    // group 0..3 -> which j

    __shared__ float sa[K_];
    __shared__ float sg[K_];
    __shared__ float wsum[4];

    // ---- stage i-row: block-local norm, then a and g=1+a^3 into LDS ----
    {
        const float4* fi4 = reinterpret_cast<const float4*>(feat + (size_t)i * K_);
        float4 v0 = fi4[tid];
        float4 v1 = fi4[tid + 256];
        float ss = v0.x * v0.x + v0.y * v0.y + v0.z * v0.z + v0.w * v0.w
                 + v1.x * v1.x + v1.y * v1.y + v1.z * v1.z + v1.w * v1.w;
#pragma unroll
        for (int o = 1; o < 64; o <<= 1) ss += __shfl_xor(ss, o, 64);
        if (lane == 0) wsum[wave] = ss;
        __syncthreads();
        const float tot = wsum[0] + wsum[1] + wsum[2] + wsum[3];
        const float rn = 1.0f / fmaxf(sqrtf(tot), EPS_);

        float4* a4w = reinterpret_cast<float4*>(sa);
        float4* g4w = reinterpret_cast<float4*>(sg);
#define STAGE(V, IDX)                                                   \
        {                                                               \
            float4 a, g;                                                \
            a.x = (V).x * rn; a.y = (V).y * rn;                         \
            a.z = (V).z * rn; a.w = (V).w * rn;                         \
            g.x = 1.0f + a.x * a.x * a.x; g.y = 1.0f + a.y * a.y * a.y; \
            g.z = 1.0f + a.z * a.z * a.z; g.w = 1.0f + a.w * a.w * a.w; \
            a4w[IDX] = a; g4w[IDX] = g;                                 \
        }
        STAGE(v0, tid)
        STAGE(v1, tid + 256)
#undef STAGE
    }
    __syncthreads();

    const int j = jg * 16 + wave * 4 + grp;
    const float4* bj = reinterpret_cast<const float4*>(feat + (size_t)j * K_);
    const float4* a4 = reinterpret_cast<const float4*>(sa);
    const float4* g4 = reinterpret_cast<const float4*>(sg);

    float du = 0.f, uu = 0.f, sab = 0.f, saq = 0.f, sqq = 0.f, sqb = 0.f, sbb = 0.f;

#pragma unroll 8
    for (int c = 0; c < 32; ++c) {
        const int idx = c * 16 + s;        // same for all 4 groups: LDS broadcast
        const float4 a = a4[idx];
        const float4 g = g4[idx];
        const float4 b = bj[idx];
#define ACC1(AX, GX, BX)                             \
        {                                            \
            const float w = (BX) * (GX);             \
            du  = fmaf((AX), w, du);                 \
            uu  = fmaf(w, w, uu);                    \
            const float p = (AX) * (BX);             \
            sab += p;                                \
            const float q = p * p;                   \
            saq = fmaf((AX), q, saq);                \
            sqq = fmaf(q, q, sqq);                   \
            sqb = fmaf(q, (BX), sqb);                \
            sbb = fmaf((BX), (BX), sbb);             \
        }
        ACC1(a.x, g.x, b.x)
        ACC1(a.y, g.y, b.y)
        ACC1(a.z, g.z, b.z)
        ACC1(a.w, g.w, b.w)
#undef ACC1
    }

    // ---- 4-step butterfly within the 16-lane group (7 sums) ----
#pragma unroll
    for (int o = 1; o < 16; o <<= 1) {
        du  += __shfl_xor(du,  o, 64);
        uu  += __shfl_xor(uu,  o, 64);
        sab += __shfl_xor(sab, o, 64);
        saq += __shfl_xor(saq, o, 64);
        sqq += __shfl_xor(sqq, o, 64);
        sqb += __shfl_xor(sqb, o, 64);
        sbb += __shfl_xor(sbb, o, 64);
    }

    // ---- per-j epilogue (all 16 lanes of the group compute the same) ----
    const float inv_t = 1.0f / TEMP_;
    const float ds = du / fmaxf(sqrtf(uu), EPS_) * inv_t;
    const float c  = 1.0f / fmaxf(sqrtf(sbb), EPS_);
    const float dv = fmaf(c, saq, sab);
    const float vv = fmaf(c * c, sqq, fmaf(2.0f * c, sqb, sbb));
    const float dn = dv / fmaxf(sqrtf(vv), EPS_) * inv_t;
    float s1 = ds;
    float s2 = __expf(ds) + 3.0f * __expf(dn);

    // ---- combine the wave's 4 j's (cross-group butterfly) ----
    s1 += __shfl_xor(s1, 16, 64); s1 += __shfl_xor(s1, 32, 64);
    s2 += __shfl_xor(s2, 16, 64); s2 += __shfl_xor(s2, 32, 64);

    __shared__ float p1[4], p2[4];
    if (lane == 0) { p1[wave] = s1; p2[wave] = s2; }
    __syncthreads();
    if (tid == 0) {
        part[blk * 2 + 0] = p1[0] + p1[1] + p1[2] + p1[3];
        part[blk * 2 + 1] = p2[0] + p2[1] + p2[2] + p2[3];
    }
}

// ---------------------------------------------------------------------------
// k_final: thread i combines its 8 group-partials, computes
// contrib_i = (1/B) * sum_j d_self - log(denom_i), reduces over i.
// ---------------------------------------------------------------------------
__global__ __launch_bounds__(128) void k_final(const float* __restrict__ part,
                                               float* __restrict__ out) {
    const int i = threadIdx.x;
    float s1 = 0.0f, s2 = 0.0f;
#pragma unroll
    for (int q = 0; q < 8; ++q) {
        s1 += part[(i * 8 + q) * 2 + 0];
        s2 += part[(i * 8 + q) * 2 + 1];
    }
    float c = s1 * (1.0f / B_) - __logf(s2);
#pragma unroll
    for (int o = 1; o < 64; o <<= 1) c += __shfl_xor(c, o, 64);
    __shared__ float wsum[2];
    const int wave = i >> 6, lane = i & 63;
    if (lane == 0) wsum[wave] = c;
    __syncthreads();
    if (i == 0) out[0] = -(wsum[0] + wsum[1]) * (1.0f / B_);
}

extern "C" void kernel_launch(void* const* d_in, const int* in_sizes, int n_in,
                              void* d_out, int out_size, void* d_ws, size_t ws_size,
                              hipStream_t stream) {
    const float* feat = (const float*)d_in[0];
    float* part = (float*)d_ws;              // 1024*2 floats
    float* out = (float*)d_out;

    k_pairs<<<NBLK_, 256, 0, stream>>>(feat, part);
    k_final<<<1, 128, 0, stream>>>(part, out);
}